// Round 8
// baseline (475.811 us; speedup 1.0000x reference)
//
#include <hip/hip_runtime.h>
#include <stdint.h>

#pragma clang fp contract(off)

#define B_ 2
#define P_ 512
#define C_ 21
#define CF 20            // foreground classes
#define G_ (B_ * CF)     // 40 groups
#define DET 100
#define SCORE_THRESH 0.05f
#define NMS_THR 0.5f
#define BBOX_CLIP 4.135166556742356f   // log(1000/16)
#define NC (CF * DET)    // 2000 candidates per image
#define PPT 4
#define TPB 256
#define NBLK 128         // pair chunks per group

typedef unsigned long long u64;
typedef unsigned int u32;

__device__ __forceinline__ u32 f2o(float f) {
  u32 u = __float_as_uint(f);
  return (u & 0x80000000u) ? ~u : (u | 0x80000000u);
}

// ---------------------------------------------------------------------------
// K1 (prep): per-(image,class) decode + rank-scatter sort (1 barrier).
// Scatters sorted-order pts / unclipped aabb / pr5 / area / score for the
// valid prefix; zeroes this group's sup slice + arrival counters; writes V.
// ---------------------------------------------------------------------------
__global__ void __launch_bounds__(256)
prep_kernel(const float* __restrict__ logits,
            const float* __restrict__ breg,
            const float* __restrict__ rrects,
            float* __restrict__ scsS,   // [G*P] sorted scores (valid prefix)
            float* __restrict__ ptsS,   // [G*P][8] sorted pts
            float* __restrict__ aabbS,  // [G*P][4] sorted unclipped aabb
            float* __restrict__ pr5S,   // [G*P][5] sorted proposals
            float* __restrict__ areaS,  // [G*P] sorted area
            int* __restrict__ gV,
            u64* __restrict__ sup,
            int* __restrict__ pairCnt,  // [G] arrival counters
            int* __restrict__ grpCnt) { // [B] arrival counters
  int g = blockIdx.x;
  int b = g / CF, cf = g % CF, c = cf + 1;
  int tid = threadIdx.x;

  __shared__ u64 lkey[P_];
  __shared__ int cnt;
  if (tid == 0) {
    cnt = 0;
    pairCnt[g] = 0;
    if (g < B_) grpCnt[g] = 0;
  }

  u64 kreg[2];
  float fx[2][4], fy[2][4], fab[2][4], fp5[2][5], far_[2], fsc[2];
  #pragma unroll
  for (int e = 0; e < 2; ++e) {
    int p = tid + e * 256;
    int n = b * P_ + p;
    const float* lg = logits + n * C_;
    float mx = lg[0];
    for (int k = 1; k < C_; ++k) mx = fmaxf(mx, lg[k]);
    float den = 0.f;
    for (int k = 0; k < C_; ++k) den += expf(lg[k] - mx);
    float sc = expf(lg[c] - mx) / den;

    const float* d = breg + n * (C_ * 5) + c * 5;
    float dx = d[0] / 10.0f, dy = d[1] / 10.0f;
    float dw = d[2] / 5.0f, dh = d[3] / 5.0f, da = d[4] / 3.0f;
    dw = fminf(dw, BBOX_CLIP);
    dh = fminf(dh, BBOX_CLIP);
    const float* an = rrects + n * 5;
    float px = dx * an[2] + an[0];
    float py = dy * an[3] + an[1];
    float pw = expf(dw) * an[2];
    float ph = expf(dh) * an[3];
    float pa = da * 57.29577951308232f + an[4];
    fp5[e][0] = px; fp5[e][1] = py; fp5[e][2] = pw; fp5[e][3] = ph; fp5[e][4] = pa;
    far_[e] = pw * ph;

    float t = pa * 0.017453292519943295f;
    float cs = cosf(t), sn = sinf(t);
    float hx = pw * 0.5f, hy = ph * 0.5f;
    float ox[4] = {-hx, hx, hx, -hx};
    float oy[4] = {-hy, -hy, hy, hy};
    float minx = 1e30f, miny = 1e30f, maxx = -1e30f, maxy = -1e30f;
    #pragma unroll
    for (int qq = 0; qq < 4; ++qq) {
      float x = px + cs * ox[qq] - sn * oy[qq];
      float y = py + sn * ox[qq] + cs * oy[qq];
      fx[e][qq] = x; fy[e][qq] = y;
      minx = fminf(minx, x); maxx = fmaxf(maxx, x);
      miny = fminf(miny, y); maxy = fmaxf(maxy, y);
    }
    fab[e][0] = minx; fab[e][1] = miny; fab[e][2] = maxx; fab[e][3] = maxy;

    bool valid = sc > SCORE_THRESH;
    float v = valid ? sc : -1.0f;
    fsc[e] = v;
    u64 key = ((u64)f2o(v) << 32) | (u32)(~(u32)p);
    lkey[p] = key;
    kreg[e] = key;
    u64 m = __ballot(valid);
    if ((tid & 63) == 0) atomicAdd(&cnt, __popcll(m));
  }
  for (int w = tid; w < P_ * 8; w += 256) sup[(size_t)g * P_ * 8 + w] = 0ull;
  __syncthreads();

  u64 k0 = kreg[0], k1 = kreg[1];
  int r0 = 0, r1 = 0;
  for (int s = 0; s < P_; ++s) {
    u64 ks = lkey[s];
    r0 += (ks > k0) ? 1 : 0;
    r1 += (ks > k1) ? 1 : 0;
  }
  #pragma unroll
  for (int e = 0; e < 2; ++e) {
    if (fsc[e] > 0.f) {
      int r = (e == 0) ? r0 : r1;
      int so = g * P_ + r;
      scsS[so] = fsc[e];
      ((float4*)ptsS)[so * 2]     = make_float4(fx[e][0], fx[e][1], fx[e][2], fx[e][3]);
      ((float4*)ptsS)[so * 2 + 1] = make_float4(fy[e][0], fy[e][1], fy[e][2], fy[e][3]);
      ((float4*)aabbS)[so] = make_float4(fab[e][0], fab[e][1], fab[e][2], fab[e][3]);
      pr5S[so * 5 + 0] = fp5[e][0]; pr5S[so * 5 + 1] = fp5[e][1];
      pr5S[so * 5 + 2] = fp5[e][2]; pr5S[so * 5 + 3] = fp5[e][3];
      pr5S[so * 5 + 4] = fp5[e][4];
      areaS[so] = far_[e];
    }
  }
  if (tid == 0) gV[g] = cnt;
}

// ---------------------------------------------------------------------------
// exact convex quad-quad intersection area — register-resident, bit-identical
// float op order vs reference (fp contract off). Clips quad q by edges of r.
// ---------------------------------------------------------------------------
__device__ __forceinline__ float inter_area_reg(const float qx[4], const float qy[4],
                                                const float rx[4], const float ry[4]) {
  float px_[8], py_[8];
  #pragma unroll
  for (int t = 0; t < 8; ++t) { px_[t] = (t < 4) ? qx[t] : 0.f; py_[t] = (t < 4) ? qy[t] : 0.f; }
  int n = 4;
  #pragma unroll
  for (int e = 0; e < 4; ++e) {
    float a0 = rx[e], a1 = ry[e];
    float b0 = rx[(e + 1) & 3], b1 = ry[(e + 1) & 3];
    float dx = b0 - a0, dy = b1 - a1;
    float ox_[8], oy_[8];
    #pragma unroll
    for (int t = 0; t < 8; ++t) { ox_[t] = 0.f; oy_[t] = 0.f; }
    float cr[8];
    #pragma unroll
    for (int t = 0; t < 8; ++t) cr[t] = dx * (py_[t] - a1) - dy * (px_[t] - a0);
    int m = 0;
    int nn = (n > 1) ? n : 1;
    #pragma unroll
    for (int t = 0; t < 8; ++t) {
      bool act = t < n;
      float sx = px_[t], sy = py_[t];
      float ex, ey, ce;
      if (t == 7) { ex = px_[0]; ey = py_[0]; ce = cr[0]; }
      else {
        bool wrap = (t + 1 == nn);
        ex = wrap ? px_[0] : px_[t + 1];
        ey = wrap ? py_[0] : py_[t + 1];
        ce = wrap ? cr[0] : cr[t + 1];
      }
      float cs = cr[t];
      float denom = cs - ce;
      float dn = (fabsf(denom) > 1e-12f) ? denom : 1e-12f;
      float tt = cs / dn;
      float ipx = sx + tt * (ex - sx);
      float ipy = sy + tt * (ey - sy);
      bool s_in = cs >= 0.f, e_in = ce >= 0.f;
      bool app1 = act && (s_in != e_in);
      #pragma unroll
      for (int s2 = 0; s2 < 8; ++s2) {
        bool wr = app1 && (m == s2);
        ox_[s2] = wr ? ipx : ox_[s2];
        oy_[s2] = wr ? ipy : oy_[s2];
      }
      m += app1 ? 1 : 0;
      bool app2 = act && e_in;
      #pragma unroll
      for (int s2 = 0; s2 < 8; ++s2) {
        bool wr = app2 && (m == s2);
        ox_[s2] = wr ? ex : ox_[s2];
        oy_[s2] = wr ? ey : oy_[s2];
      }
      m += app2 ? 1 : 0;
    }
    n = m;
    #pragma unroll
    for (int t = 0; t < 8; ++t) { px_[t] = ox_[t]; py_[t] = oy_[t]; }
  }
  int nn = (n > 1) ? n : 1;
  float s = 0.f;
  #pragma unroll
  for (int t = 0; t < 8; ++t) {
    if (t < n) {
      float nx_x, nx_y;
      if (t == 7) { nx_x = px_[0]; nx_y = py_[0]; }
      else {
        bool wrap = (t + 1 == nn);
        nx_x = wrap ? px_[0] : px_[t + 1];
        nx_y = wrap ? py_[0] : py_[t + 1];
      }
      s += px_[t] * nx_y - nx_x * py_[t];
    }
  }
  float area = 0.5f * fabsf(s);
  return (n >= 3) ? area : 0.f;
}

// ---------------------------------------------------------------------------
// K2 (mega): pair IoU phase on all blocks; the LAST-arriving block per group
// runs greedy NMS + emit; the LAST group per image runs the top-100 rank.
// Inter-block deps via device-scope arrival counters (no spinning).
// ---------------------------------------------------------------------------
__global__ void __launch_bounds__(256)
mega_kernel(const int* __restrict__ gV,
            const float* __restrict__ aabbS,
            const float* __restrict__ areaS,
            const float* __restrict__ ptsS,
            const float* __restrict__ scsS,
            const float* __restrict__ pr5S,
            u64* __restrict__ sup,
            u64* __restrict__ cand,
            float* __restrict__ rec,
            float* __restrict__ out,
            int* __restrict__ pairCnt,
            int* __restrict__ grpCnt) {
  int g = blockIdx.y;
  int tid = threadIdx.x;
  __shared__ u64 shbuf[P_ * 8];        // 32 KB, aliased per phase
  __shared__ int scnt;
  __shared__ int amLast;

  // ---- pair phase ----
  {
    int V = gV[g];
    int Tp = V * (V - 1) / 2;
    int base = blockIdx.x * (TPB * PPT);
    if (base < Tp) {
      u32* q = (u32*)shbuf;
      if (tid == 0) scnt = 0;
      __syncthreads();
      const float4* ab = (const float4*)aabbS;
      #pragma unroll
      for (int t = 0; t < PPT; ++t) {
        int kk = base + t * TPB + tid;
        if (kk >= Tp) break;
        float kf = (float)kk;
        int i = (int)((1.0f + sqrtf(1.0f + 8.0f * kf)) * 0.5f);
        while (i * (i - 1) / 2 > kk) --i;
        while ((i + 1) * i / 2 <= kk) ++i;
        int j = kk - i * (i - 1) / 2;
        float4 bi = ab[g * P_ + i];
        float4 bj = ab[g * P_ + j];
        bool ov = (bi.x <= bj.z) && (bj.x <= bi.z) && (bi.y <= bj.w) && (bj.y <= bi.w);
        if (ov) {
          int s = atomicAdd(&scnt, 1);
          q[s] = (u32)((i << 9) | j);
        }
      }
      __syncthreads();
      int nq = scnt;
      const float4* pS = (const float4*)ptsS;
      for (int s = tid; s < nq; s += TPB) {
        u32 pk = q[s];
        int i = (int)(pk >> 9), j = (int)(pk & 511);
        float4 ax = pS[(g * P_ + i) * 2];
        float4 ay = pS[(g * P_ + i) * 2 + 1];
        float4 bx = pS[(g * P_ + j) * 2];
        float4 by = pS[(g * P_ + j) * 2 + 1];
        float qx[4] = {ax.x, ax.y, ax.z, ax.w};
        float qy[4] = {ay.x, ay.y, ay.z, ay.w};
        float rx[4] = {bx.x, bx.y, bx.z, bx.w};
        float ry[4] = {by.x, by.y, by.z, by.w};
        float ai = areaS[g * P_ + i];
        float aj = areaS[g * P_ + j];
        // reference iou[i][j]: clip quad i by edges of quad j
        float inter = inter_area_reg(qx, qy, rx, ry);
        float iou = inter / (((ai + aj) - inter) + 1e-8f);
        if (iou > NMS_THR)
          atomicOr(&sup[((size_t)g * P_ + i) * 8 + (j >> 6)], 1ull << (j & 63));
      }
    }
  }

  // ---- arrival on group counter; last block runs greedy ----
  __syncthreads();
  __threadfence();                               // release sup writes
  if (tid == 0) amLast = (atomicAdd(&pairCnt[g], 1) == NBLK - 1) ? 1 : 0;
  __syncthreads();
  if (!amLast) return;
  __threadfence();                               // acquire other blocks' sup

  // ---- greedy phase (this block only) ----
  {
    u64* lsup = shbuf;
    __shared__ u32 skeep[16];
    int V = gV[g];
    for (int w = tid; w < V * 8; w += TPB) lsup[w] = sup[(size_t)g * P_ * 8 + w];
    __syncthreads();
    if (tid < 64) {
      u64 keepw = 0;
      u64 cur = (tid < 8 && V > 0) ? lsup[tid] : 0ull;
      for (int i = 0; i < V; ++i) {
        u64 nxt = (tid < 8 && (i + 1) < V) ? lsup[(i + 1) * 8 + tid] : 0ull;
        bool supd = __any((cur & keepw) != 0ull);
        if (!supd && tid == (i >> 6)) keepw |= 1ull << (i & 63);
        cur = nxt;
      }
      if (tid < 8) { skeep[tid * 2] = (u32)keepw; skeep[tid * 2 + 1] = (u32)(keepw >> 32); }
    }
    __syncthreads();
    int cls = g % CF;
    int tot = 0;
    #pragma unroll
    for (int t = 0; t < 16; ++t) tot += __popc(skeep[t]);
    for (int r = tid; r < V; r += TPB) {
      if ((skeep[r >> 5] >> (r & 31)) & 1u) {
        int slot = __popc(skeep[r >> 5] & ((1u << (r & 31)) - 1u));
        for (int t = 0; t < (r >> 5); ++t) slot += __popc(skeep[t]);
        if (slot < DET) {
          float sv = scsS[g * P_ + r];
          int flat = cls * P_ + r;
          cand[g * DET + slot] = ((u64)f2o(sv) << 32) | (u32)(~(u32)flat);
          int so = g * P_ + r;
          float* rr = rec + (size_t)(g * DET + slot) * 12;
          rr[0] = fminf(fmaxf(aabbS[so * 4 + 0], 0.f), 1023.0f);
          rr[1] = fminf(fmaxf(aabbS[so * 4 + 1], 0.f), 799.0f);
          rr[2] = fminf(fmaxf(aabbS[so * 4 + 2], 0.f), 1023.0f);
          rr[3] = fminf(fmaxf(aabbS[so * 4 + 3], 0.f), 799.0f);
          rr[4] = pr5S[so * 5 + 0]; rr[5] = pr5S[so * 5 + 1]; rr[6] = pr5S[so * 5 + 2];
          rr[7] = pr5S[so * 5 + 3]; rr[8] = pr5S[so * 5 + 4];
          rr[9] = sv;
          rr[10] = (float)(cls + 1);
          rr[11] = 0.f;
        }
      }
    }
    int fill = tot < DET ? tot : DET;
    for (int s = fill + tid; s < DET; s += TPB) cand[g * DET + s] = 0ull;
  }

  // ---- arrival on image counter; last group runs rank ----
  __syncthreads();
  __threadfence();                               // release cand/rec writes
  int b = g / CF;
  if (tid == 0) amLast = (atomicAdd(&grpCnt[b], 1) == CF - 1) ? 1 : 0;
  __syncthreads();
  if (!amLast) return;
  __threadfence();                               // acquire other groups' cand

  // ---- rank phase (one block per image) ----
  {
    u64* lc = shbuf;                             // 2000 u64 = 16 KB
    if (tid == 0) scnt = 0;
    __syncthreads();
    int nz = 0;
    for (int i = tid; i < NC; i += TPB) {
      u64 v = cand[b * NC + i];
      lc[i] = v;
      nz += (v != 0ull) ? 1 : 0;
    }
    if (nz > 0) atomicAdd(&scnt, nz);
    __syncthreads();
    int nc = scnt;
    for (int row = nc + tid; row < DET; row += TPB) {
      int o_bb = (b * DET + row) * 4;
      int o_rr = B_ * DET * 4 + (b * DET + row) * 5;
      int o_sc = B_ * DET * 9 + b * DET + row;
      int o_lab = B_ * DET * 10 + b * DET + row;
      out[o_bb + 0] = 0.f; out[o_bb + 1] = 0.f; out[o_bb + 2] = 0.f; out[o_bb + 3] = 0.f;
      out[o_rr + 0] = 0.f; out[o_rr + 1] = 0.f; out[o_rr + 2] = 0.f;
      out[o_rr + 3] = 0.f; out[o_rr + 4] = 0.f;
      out[o_sc] = 0.f;
      out[o_lab] = 0.f;
    }
    for (int ci = tid; ci < NC; ci += TPB) {
      u64 k = lc[ci];
      if (k == 0ull) continue;
      int rank = 0;
      #pragma unroll
      for (int gp = 0; gp < CF; ++gp) {
        int lo = 0, hi = DET;
        while (lo < hi) {          // first idx with lc[gp*DET+idx] <= k (desc)
          int mid = (lo + hi) >> 1;
          if (lc[gp * DET + mid] > k) lo = mid + 1; else hi = mid;
        }
        rank += lo;
      }
      if (rank >= DET) continue;
      const float* rr = rec + (size_t)(b * NC + ci) * 12;
      int o_bb = (b * DET + rank) * 4;
      int o_rr = B_ * DET * 4 + (b * DET + rank) * 5;
      int o_sc = B_ * DET * 9 + b * DET + rank;
      int o_lab = B_ * DET * 10 + b * DET + rank;
      out[o_bb + 0] = rr[0]; out[o_bb + 1] = rr[1];
      out[o_bb + 2] = rr[2]; out[o_bb + 3] = rr[3];
      out[o_rr + 0] = rr[4]; out[o_rr + 1] = rr[5]; out[o_rr + 2] = rr[6];
      out[o_rr + 3] = rr[7]; out[o_rr + 4] = rr[8];
      out[o_sc] = rr[9];
      out[o_lab] = rr[10];
    }
  }
}

// ---------------------------------------------------------------------------
extern "C" void kernel_launch(void* const* d_in, const int* in_sizes, int n_in,
                              void* d_out, int out_size, void* d_ws, size_t ws_size,
                              hipStream_t stream) {
  const float* logits = (const float*)d_in[0];
  const float* breg   = (const float*)d_in[1];
  const float* rrects = (const float*)d_in[2];
  float* out = (float*)d_out;

  u64*   sup    = (u64*)d_ws;                         // G*P*8 u64
  u64*   cand   = sup + (size_t)G_ * P_ * 8;          // G*DET u64
  int*   gV     = (int*)(cand + G_ * DET);            // 64 ints
  int*   pairCnt = gV + 64;                           // 64 ints
  int*   grpCnt  = pairCnt + 64;                      // 16 ints
  float* scsS   = (float*)(grpCnt + 16);              // G*P
  float* ptsS   = scsS + (size_t)G_ * P_;             // G*P*8
  float* aabbS  = ptsS + (size_t)G_ * P_ * 8;         // G*P*4
  float* pr5S   = aabbS + (size_t)G_ * P_ * 4;        // G*P*5
  float* areaS  = pr5S + (size_t)G_ * P_ * 5;         // G*P
  float* rec    = areaS + (size_t)G_ * P_;            // G*DET*12

  prep_kernel<<<G_, 256, 0, stream>>>(logits, breg, rrects,
                                      scsS, ptsS, aabbS, pr5S, areaS, gV, sup,
                                      pairCnt, grpCnt);
  mega_kernel<<<dim3(NBLK, G_), TPB, 0, stream>>>(gV, aabbS, areaS, ptsS,
                                                  scsS, pr5S, sup, cand, rec,
                                                  out, pairCnt, grpCnt);
}

// Round 9
// 202.921 us; speedup vs baseline: 2.3448x; 2.3448x over previous
//
#include <hip/hip_runtime.h>
#include <stdint.h>

#pragma clang fp contract(off)

#define B_ 2
#define P_ 512
#define C_ 21
#define CF 20            // foreground classes
#define G_ (B_ * CF)     // 40 groups
#define DET 100
#define SCORE_THRESH 0.05f
#define NMS_THR 0.5f
#define BBOX_CLIP 4.135166556742356f   // log(1000/16)
#define NC (CF * DET)    // 2000 candidates per image
#define TRI 130816       // 512*511/2 pairs per group
#define TRIPAD 131072
#define TPB 256
#define NBX 32           // pair blocks per group
#define CHUNK 1024       // pairs per block-chunk

typedef unsigned long long u64;
typedef unsigned int u32;
typedef unsigned char u8;

__device__ __forceinline__ u32 f2o(float f) {
  u32 u = __float_as_uint(f);
  return (u & 0x80000000u) ? ~u : (u | 0x80000000u);
}
__device__ __forceinline__ float o2f(u32 o) {
  u32 u = (o & 0x80000000u) ? (o ^ 0x80000000u) : ~o;
  return __uint_as_float(u);
}

// ---------------------------------------------------------------------------
// exact convex quad-quad intersection area — register-resident, bit-identical
// float op order vs reference (fp contract off). Clips quad q by edges of r.
// ---------------------------------------------------------------------------
__device__ __forceinline__ float inter_area_reg(const float qx[4], const float qy[4],
                                                const float rx[4], const float ry[4]) {
  float px_[8], py_[8];
  #pragma unroll
  for (int t = 0; t < 8; ++t) { px_[t] = (t < 4) ? qx[t] : 0.f; py_[t] = (t < 4) ? qy[t] : 0.f; }
  int n = 4;
  #pragma unroll
  for (int e = 0; e < 4; ++e) {
    float a0 = rx[e], a1 = ry[e];
    float b0 = rx[(e + 1) & 3], b1 = ry[(e + 1) & 3];
    float dx = b0 - a0, dy = b1 - a1;
    float ox_[8], oy_[8];
    #pragma unroll
    for (int t = 0; t < 8; ++t) { ox_[t] = 0.f; oy_[t] = 0.f; }
    float cr[8];
    #pragma unroll
    for (int t = 0; t < 8; ++t) cr[t] = dx * (py_[t] - a1) - dy * (px_[t] - a0);
    int m = 0;
    int nn = (n > 1) ? n : 1;
    #pragma unroll
    for (int t = 0; t < 8; ++t) {
      bool act = t < n;
      float sx = px_[t], sy = py_[t];
      float ex, ey, ce;
      if (t == 7) { ex = px_[0]; ey = py_[0]; ce = cr[0]; }
      else {
        bool wrap = (t + 1 == nn);
        ex = wrap ? px_[0] : px_[t + 1];
        ey = wrap ? py_[0] : py_[t + 1];
        ce = wrap ? cr[0] : cr[t + 1];
      }
      float cs = cr[t];
      float denom = cs - ce;
      float dn = (fabsf(denom) > 1e-12f) ? denom : 1e-12f;
      float tt = cs / dn;
      float ipx = sx + tt * (ex - sx);
      float ipy = sy + tt * (ey - sy);
      bool s_in = cs >= 0.f, e_in = ce >= 0.f;
      bool app1 = act && (s_in != e_in);
      #pragma unroll
      for (int s2 = 0; s2 < 8; ++s2) {
        bool wr = app1 && (m == s2);
        ox_[s2] = wr ? ipx : ox_[s2];
        oy_[s2] = wr ? ipy : oy_[s2];
      }
      m += app1 ? 1 : 0;
      bool app2 = act && e_in;
      #pragma unroll
      for (int s2 = 0; s2 < 8; ++s2) {
        bool wr = app2 && (m == s2);
        ox_[s2] = wr ? ex : ox_[s2];
        oy_[s2] = wr ? ey : oy_[s2];
      }
      m += app2 ? 1 : 0;
    }
    n = m;
    #pragma unroll
    for (int t = 0; t < 8; ++t) { px_[t] = ox_[t]; py_[t] = oy_[t]; }
  }
  int nn = (n > 1) ? n : 1;
  float s = 0.f;
  #pragma unroll
  for (int t = 0; t < 8; ++t) {
    if (t < n) {
      float nx_x, nx_y;
      if (t == 7) { nx_x = px_[0]; nx_y = py_[0]; }
      else {
        bool wrap = (t + 1 == nn);
        nx_x = wrap ? px_[0] : px_[t + 1];
        nx_y = wrap ? py_[0] : py_[t + 1];
      }
      s += px_[t] * nx_y - nx_x * py_[t];
    }
  }
  float area = 0.5f * fabsf(s);
  return (n >= 3) ? area : 0.f;
}

// ---------------------------------------------------------------------------
// D1 (pairdec): each block redundantly decodes its whole group into LDS
// (unsorted index space), then processes its share of the tri(512) pair
// domain: validity+AABB reject -> LDS queue -> exact clip. One byte per pair
// (exactly one writer) => no atomics, no pre-zeroed state anywhere.
// Block x==0 also publishes keys + payload for D2/D3.
// ---------------------------------------------------------------------------
__global__ void __launch_bounds__(256)
pairdec_kernel(const float* __restrict__ logits,
               const float* __restrict__ breg,
               const float* __restrict__ rrects,
               u8* __restrict__ sup8,     // [G][TRIPAD] pair bytes
               u64* __restrict__ keyG,    // [G*P] keys (unsorted)
               float* __restrict__ aabbG, // [G*P][4] unclipped aabb (unsorted)
               float* __restrict__ pr5G) {// [G*P][5] proposals (unsorted)
  int g = blockIdx.y;
  int bx = blockIdx.x;
  int tid = threadIdx.x;
  int b = g / CF, cf = g % CF, c = cf + 1;

  __shared__ float lptx[P_][4];
  __shared__ float lpty[P_][4];
  __shared__ float lab[P_][4];
  __shared__ float larea[P_];
  __shared__ u64 lkey[P_];
  __shared__ u32 q[CHUNK];
  __shared__ int qn;

  // ---- decode 2 proposals/thread into LDS (identical arithmetic to ref) ----
  #pragma unroll
  for (int e = 0; e < 2; ++e) {
    int p = tid + e * 256;
    int n = b * P_ + p;
    const float* lg = logits + n * C_;
    float mx = lg[0];
    for (int k = 1; k < C_; ++k) mx = fmaxf(mx, lg[k]);
    float den = 0.f;
    for (int k = 0; k < C_; ++k) den += expf(lg[k] - mx);
    float sc = expf(lg[c] - mx) / den;

    const float* d = breg + n * (C_ * 5) + c * 5;
    float dx = d[0] / 10.0f, dy = d[1] / 10.0f;
    float dw = d[2] / 5.0f, dh = d[3] / 5.0f, da = d[4] / 3.0f;
    dw = fminf(dw, BBOX_CLIP);
    dh = fminf(dh, BBOX_CLIP);
    const float* an = rrects + n * 5;
    float px = dx * an[2] + an[0];
    float py = dy * an[3] + an[1];
    float pw = expf(dw) * an[2];
    float ph = expf(dh) * an[3];
    float pa = da * 57.29577951308232f + an[4];
    larea[p] = pw * ph;

    float t = pa * 0.017453292519943295f;
    float cs = cosf(t), sn = sinf(t);
    float hx = pw * 0.5f, hy = ph * 0.5f;
    float ox[4] = {-hx, hx, hx, -hx};
    float oy[4] = {-hy, -hy, hy, hy};
    float minx = 1e30f, miny = 1e30f, maxx = -1e30f, maxy = -1e30f;
    #pragma unroll
    for (int qq = 0; qq < 4; ++qq) {
      float x = px + cs * ox[qq] - sn * oy[qq];
      float y = py + sn * ox[qq] + cs * oy[qq];
      lptx[p][qq] = x; lpty[p][qq] = y;
      minx = fminf(minx, x); maxx = fmaxf(maxx, x);
      miny = fminf(miny, y); maxy = fmaxf(maxy, y);
    }
    lab[p][0] = minx; lab[p][1] = miny; lab[p][2] = maxx; lab[p][3] = maxy;

    bool valid = sc > SCORE_THRESH;
    float v = valid ? sc : -1.0f;
    u64 key = ((u64)f2o(v) << 32) | (u32)(~(u32)p);
    lkey[p] = key;

    if (bx == 0) {       // publish payload once per group
      keyG[g * P_ + p] = key;
      ((float4*)aabbG)[g * P_ + p] = make_float4(minx, miny, maxx, maxy);
      float* pp = pr5G + (size_t)(g * P_ + p) * 5;
      pp[0] = px; pp[1] = py; pp[2] = pw; pp[3] = ph; pp[4] = pa;
    }
  }
  __syncthreads();

  // ---- pair domain, chunk-strided over this group's 32 blocks ----
  u8* S = sup8 + (size_t)g * TRIPAD;
  for (int ch = bx; ch * CHUNK < TRI; ch += NBX) {
    int base = ch * CHUNK;
    if (tid == 0) qn = 0;
    __syncthreads();
    #pragma unroll
    for (int t = 0; t < 4; ++t) {
      int kk = base + t * TPB + tid;
      if (kk >= TRI) break;
      float kf = (float)kk;
      int p = (int)((1.0f + sqrtf(1.0f + 8.0f * kf)) * 0.5f);
      while (p * (p - 1) / 2 > kk) --p;
      while ((p + 1) * p / 2 <= kk) ++p;
      int qq = kk - p * (p - 1) / 2;
      bool vv = ((u32)(lkey[p] >> 32) > 0x80000000u) &&
                ((u32)(lkey[qq] >> 32) > 0x80000000u);
      bool ov = vv && (lab[p][0] <= lab[qq][2]) && (lab[qq][0] <= lab[p][2]) &&
                      (lab[p][1] <= lab[qq][3]) && (lab[qq][1] <= lab[p][3]);
      if (ov) {
        int s = atomicAdd(&qn, 1);
        q[s] = ((u32)p << 16) | (u32)qq;
      } else {
        S[kk] = 0;
      }
    }
    __syncthreads();
    int nq = qn;
    for (int s = tid; s < nq; s += TPB) {
      u32 pk = q[s];
      int p = (int)(pk >> 16), qq = (int)(pk & 0xffff);
      // reference clips the LOWER-scored quad by edges of the HIGHER-scored
      int hi, lo;
      if (lkey[p] > lkey[qq]) { hi = p; lo = qq; } else { hi = qq; lo = p; }
      float qx[4] = {lptx[lo][0], lptx[lo][1], lptx[lo][2], lptx[lo][3]};
      float qy[4] = {lpty[lo][0], lpty[lo][1], lpty[lo][2], lpty[lo][3]};
      float rx[4] = {lptx[hi][0], lptx[hi][1], lptx[hi][2], lptx[hi][3]};
      float ry[4] = {lpty[hi][0], lpty[hi][1], lpty[hi][2], lpty[hi][3]};
      float inter = inter_area_reg(qx, qy, rx, ry);
      float iou = inter / (((larea[lo] + larea[hi]) - inter) + 1e-8f);
      int kk = p * (p - 1) / 2 + qq;
      S[kk] = (iou > NMS_THR) ? (u8)1 : (u8)0;
    }
    __syncthreads();
  }
}

// ---------------------------------------------------------------------------
// D2 (greedy): per-group rank sort of keys, byte-matrix scan -> rank-space
// LDS bitmatrix, wave-0 greedy chain, emit cand keys + 12-float records.
// ---------------------------------------------------------------------------
__global__ void __launch_bounds__(256)
greedy_kernel(const u64* __restrict__ keyG, const u8* __restrict__ sup8,
              const float* __restrict__ aabbG, const float* __restrict__ pr5G,
              u64* __restrict__ cand, float* __restrict__ rec) {
  int g = blockIdx.x;
  int tid = threadIdx.x;
  __shared__ u64 lkey[P_];
  __shared__ short rankOf[P_];
  __shared__ short sidx[P_];
  __shared__ u32 supb[P_][16];      // 32 KB rank-space bitmatrix
  __shared__ u32 skeep[16];
  __shared__ int sV;
  if (tid == 0) sV = 0;
  for (int i = tid; i < P_; i += TPB) lkey[i] = keyG[g * P_ + i];
  for (int w = tid; w < P_ * 16; w += TPB) ((u32*)supb)[w] = 0u;
  __syncthreads();

  // rank-scatter (keys distinct)
  #pragma unroll
  for (int e = 0; e < 2; ++e) {
    int p = tid + e * 256;
    u64 k = lkey[p];
    int r = 0;
    for (int s = 0; s < P_; ++s) r += (lkey[s] > k) ? 1 : 0;
    rankOf[p] = (short)r;
    sidx[r] = (short)p;
    bool valid = ((u32)(k >> 32)) > 0x80000000u;
    u64 m = __ballot(valid);
    if ((tid & 63) == 0) atomicAdd(&sV, __popcll(m));
  }
  __syncthreads();
  int V = sV;

  // scan byte matrix -> set rank-space bits
  const u32* S32 = (const u32*)(sup8 + (size_t)g * TRIPAD);
  for (int w = tid; w < TRI / 4; w += TPB) {
    u32 v = S32[w];
    if (v == 0u) continue;
    #pragma unroll
    for (int bt = 0; bt < 4; ++bt) {
      if ((v >> (bt * 8)) & 0xffu) {
        int kk = w * 4 + bt;
        float kf = (float)kk;
        int p = (int)((1.0f + sqrtf(1.0f + 8.0f * kf)) * 0.5f);
        while (p * (p - 1) / 2 > kk) --p;
        while ((p + 1) * p / 2 <= kk) ++p;
        int qq = kk - p * (p - 1) / 2;
        int i = rankOf[p], j = rankOf[qq];
        int row = (i > j) ? i : j;
        int col = (i > j) ? j : i;
        atomicOr(&supb[row][col >> 5], 1u << (col & 31));
      }
    }
  }
  __syncthreads();

  // wave-0 sequential greedy chain
  if (tid < 64) {
    u32 keepw = 0;
    u32 cur = (tid < 16 && V > 0) ? supb[0][tid] : 0u;
    for (int i = 0; i < V; ++i) {
      u32 nxt = (tid < 16 && (i + 1) < V) ? supb[i + 1][tid] : 0u;
      bool supd = __any((cur & keepw) != 0u);
      if (!supd && tid == (i >> 5)) keepw |= 1u << (i & 31);
      cur = nxt;
    }
    if (tid < 16) skeep[tid] = keepw;
  }
  __syncthreads();

  // emit
  int cls = g % CF;
  int tot = 0;
  #pragma unroll
  for (int t = 0; t < 16; ++t) tot += __popc(skeep[t]);
  for (int r = tid; r < V; r += TPB) {
    if ((skeep[r >> 5] >> (r & 31)) & 1u) {
      int slot = __popc(skeep[r >> 5] & ((1u << (r & 31)) - 1u));
      for (int t = 0; t < (r >> 5); ++t) slot += __popc(skeep[t]);
      if (slot < DET) {
        int p = sidx[r];
        u64 k = lkey[p];
        float sv = o2f((u32)(k >> 32));
        int flat = cls * P_ + r;
        cand[g * DET + slot] = (k & 0xffffffff00000000ull) | (u32)(~(u32)flat);
        float4 ab = ((const float4*)aabbG)[g * P_ + p];
        const float* pp = pr5G + (size_t)(g * P_ + p) * 5;
        float* rr = rec + (size_t)(g * DET + slot) * 12;
        rr[0] = fminf(fmaxf(ab.x, 0.f), 1023.0f);
        rr[1] = fminf(fmaxf(ab.y, 0.f), 799.0f);
        rr[2] = fminf(fmaxf(ab.z, 0.f), 1023.0f);
        rr[3] = fminf(fmaxf(ab.w, 0.f), 799.0f);
        rr[4] = pp[0]; rr[5] = pp[1]; rr[6] = pp[2];
        rr[7] = pp[3]; rr[8] = pp[4];
        rr[9] = sv;
        rr[10] = (float)(cls + 1);
        rr[11] = 0.f;
      }
    }
  }
  int fill = tot < DET ? tot : DET;
  for (int s = fill + tid; s < DET; s += TPB) cand[g * DET + s] = 0ull;
}

// ---------------------------------------------------------------------------
// D3 (rank): per-image top-100 by binary-search rank; scatter record to row
// `rank`; zero-fill unused rows in-kernel.
// out layout: bb[2,100,4] | rr[2,100,5] | sc[2,100] | lab[2,100] (all f32)
// ---------------------------------------------------------------------------
__global__ void rank_kernel(const u64* __restrict__ cand, const float* __restrict__ rec,
                            float* __restrict__ out) {
  int b = blockIdx.y;
  int tid = threadIdx.x;
  __shared__ u64 lc[NC];
  __shared__ int ncand;
  if (tid == 0) ncand = 0;
  __syncthreads();
  int nz = 0;
  for (int i = tid; i < NC; i += 256) {
    u64 v = cand[b * NC + i];
    lc[i] = v;
    nz += (v != 0ull) ? 1 : 0;
  }
  if (nz > 0) atomicAdd(&ncand, nz);
  __syncthreads();
  int ci = blockIdx.x * 256 + tid;
  if (ci >= NC) return;
  int nc = ncand;
  if (blockIdx.x == 0 && tid < DET && tid >= nc) {
    int o_bb = (b * DET + tid) * 4;
    int o_rr = B_ * DET * 4 + (b * DET + tid) * 5;
    int o_sc = B_ * DET * 9 + b * DET + tid;
    int o_lab = B_ * DET * 10 + b * DET + tid;
    out[o_bb + 0] = 0.f; out[o_bb + 1] = 0.f; out[o_bb + 2] = 0.f; out[o_bb + 3] = 0.f;
    out[o_rr + 0] = 0.f; out[o_rr + 1] = 0.f; out[o_rr + 2] = 0.f;
    out[o_rr + 3] = 0.f; out[o_rr + 4] = 0.f;
    out[o_sc] = 0.f;
    out[o_lab] = 0.f;
  }
  u64 k = lc[ci];
  if (k == 0ull) return;
  int rank = 0;
  #pragma unroll
  for (int gp = 0; gp < CF; ++gp) {
    int lo = 0, hi = DET;
    while (lo < hi) {            // first idx with lc[gp*DET+idx] <= k (desc list)
      int mid = (lo + hi) >> 1;
      if (lc[gp * DET + mid] > k) lo = mid + 1; else hi = mid;
    }
    rank += lo;
  }
  if (rank >= DET) return;
  const float* rr = rec + (size_t)(b * NC + ci) * 12;
  int o_bb = (b * DET + rank) * 4;
  int o_rr = B_ * DET * 4 + (b * DET + rank) * 5;
  int o_sc = B_ * DET * 9 + b * DET + rank;
  int o_lab = B_ * DET * 10 + b * DET + rank;
  out[o_bb + 0] = rr[0]; out[o_bb + 1] = rr[1];
  out[o_bb + 2] = rr[2]; out[o_bb + 3] = rr[3];
  out[o_rr + 0] = rr[4]; out[o_rr + 1] = rr[5]; out[o_rr + 2] = rr[6];
  out[o_rr + 3] = rr[7]; out[o_rr + 4] = rr[8];
  out[o_sc] = rr[9];
  out[o_lab] = rr[10];
}

// ---------------------------------------------------------------------------
extern "C" void kernel_launch(void* const* d_in, const int* in_sizes, int n_in,
                              void* d_out, int out_size, void* d_ws, size_t ws_size,
                              hipStream_t stream) {
  const float* logits = (const float*)d_in[0];
  const float* breg   = (const float*)d_in[1];
  const float* rrects = (const float*)d_in[2];
  float* out = (float*)d_out;

  u8*    sup8  = (u8*)d_ws;                           // G*TRIPAD bytes (5.24 MB)
  u64*   keyG  = (u64*)(sup8 + (size_t)G_ * TRIPAD);  // G*P u64
  u64*   cand  = keyG + (size_t)G_ * P_;              // G*DET u64
  float* aabbG = (float*)(cand + G_ * DET);           // G*P*4
  float* pr5G  = aabbG + (size_t)G_ * P_ * 4;         // G*P*5
  float* rec   = pr5G + (size_t)G_ * P_ * 5;          // G*DET*12

  pairdec_kernel<<<dim3(NBX, G_), TPB, 0, stream>>>(logits, breg, rrects,
                                                    sup8, keyG, aabbG, pr5G);
  greedy_kernel<<<G_, TPB, 0, stream>>>(keyG, sup8, aabbG, pr5G, cand, rec);
  rank_kernel<<<dim3(8, B_), TPB, 0, stream>>>(cand, rec, out);
}

// Round 10
// 183.803 us; speedup vs baseline: 2.5887x; 1.1040x over previous
//
#include <hip/hip_runtime.h>
#include <stdint.h>

#pragma clang fp contract(off)

#define B_ 2
#define P_ 512
#define C_ 21
#define CF 20            // foreground classes
#define G_ (B_ * CF)     // 40 groups
#define DET 100
#define SCORE_THRESH 0.05f
#define NMS_THR 0.5f
#define BBOX_CLIP 4.135166556742356f   // log(1000/16)
#define NC (CF * DET)    // 2000 candidates per image
#define TPB 256
#define NBX 32           // pair blocks per group (chunk-strided)
#define CHUNK 1024       // pairs per chunk

typedef unsigned long long u64;
typedef unsigned int u32;

__device__ __forceinline__ u32 f2o(float f) {
  u32 u = __float_as_uint(f);
  return (u & 0x80000000u) ? ~u : (u | 0x80000000u);
}

// ---------------------------------------------------------------------------
// K1 (prep): per-(image,class) decode + rank-scatter sort (1 barrier).
// Scatters sorted-order pts / unclipped aabb / pr5 / area / score for the
// valid prefix; zeroes this group's sup slice + image arrival counters.
// ---------------------------------------------------------------------------
__global__ void __launch_bounds__(256)
prep_kernel(const float* __restrict__ logits,
            const float* __restrict__ breg,
            const float* __restrict__ rrects,
            float* __restrict__ scsS,   // [G*P] sorted scores (valid prefix)
            float* __restrict__ ptsS,   // [G*P][8] sorted pts
            float* __restrict__ aabbS,  // [G*P][4] sorted unclipped aabb
            float* __restrict__ pr5S,   // [G*P][5] sorted proposals
            float* __restrict__ areaS,  // [G*P] sorted area
            int* __restrict__ gV,
            u64* __restrict__ sup,
            int* __restrict__ grpCnt) { // [B] arrival counters
  int g = blockIdx.x;
  int b = g / CF, cf = g % CF, c = cf + 1;
  int tid = threadIdx.x;

  __shared__ u64 lkey[P_];
  __shared__ int cnt;
  if (tid == 0) {
    cnt = 0;
    if (g < B_) grpCnt[g] = 0;
  }

  u64 kreg[2];
  float fx[2][4], fy[2][4], fab[2][4], fp5[2][5], far_[2], fsc[2];
  #pragma unroll
  for (int e = 0; e < 2; ++e) {
    int p = tid + e * 256;
    int n = b * P_ + p;
    const float* lg = logits + n * C_;
    float mx = lg[0];
    for (int k = 1; k < C_; ++k) mx = fmaxf(mx, lg[k]);
    float den = 0.f;
    for (int k = 0; k < C_; ++k) den += expf(lg[k] - mx);
    float sc = expf(lg[c] - mx) / den;

    const float* d = breg + n * (C_ * 5) + c * 5;
    float dx = d[0] / 10.0f, dy = d[1] / 10.0f;
    float dw = d[2] / 5.0f, dh = d[3] / 5.0f, da = d[4] / 3.0f;
    dw = fminf(dw, BBOX_CLIP);
    dh = fminf(dh, BBOX_CLIP);
    const float* an = rrects + n * 5;
    float px = dx * an[2] + an[0];
    float py = dy * an[3] + an[1];
    float pw = expf(dw) * an[2];
    float ph = expf(dh) * an[3];
    float pa = da * 57.29577951308232f + an[4];
    fp5[e][0] = px; fp5[e][1] = py; fp5[e][2] = pw; fp5[e][3] = ph; fp5[e][4] = pa;
    far_[e] = pw * ph;

    float t = pa * 0.017453292519943295f;
    float cs = cosf(t), sn = sinf(t);
    float hx = pw * 0.5f, hy = ph * 0.5f;
    float ox[4] = {-hx, hx, hx, -hx};
    float oy[4] = {-hy, -hy, hy, hy};
    float minx = 1e30f, miny = 1e30f, maxx = -1e30f, maxy = -1e30f;
    #pragma unroll
    for (int qq = 0; qq < 4; ++qq) {
      float x = px + cs * ox[qq] - sn * oy[qq];
      float y = py + sn * ox[qq] + cs * oy[qq];
      fx[e][qq] = x; fy[e][qq] = y;
      minx = fminf(minx, x); maxx = fmaxf(maxx, x);
      miny = fminf(miny, y); maxy = fmaxf(maxy, y);
    }
    fab[e][0] = minx; fab[e][1] = miny; fab[e][2] = maxx; fab[e][3] = maxy;

    bool valid = sc > SCORE_THRESH;
    float v = valid ? sc : -1.0f;
    fsc[e] = v;
    u64 key = ((u64)f2o(v) << 32) | (u32)(~(u32)p);
    lkey[p] = key;
    kreg[e] = key;
    u64 m = __ballot(valid);
    if ((tid & 63) == 0) atomicAdd(&cnt, __popcll(m));
  }
  for (int w = tid; w < P_ * 8; w += 256) sup[(size_t)g * P_ * 8 + w] = 0ull;
  __syncthreads();

  u64 k0 = kreg[0], k1 = kreg[1];
  int r0 = 0, r1 = 0;
  for (int s = 0; s < P_; ++s) {
    u64 ks = lkey[s];
    r0 += (ks > k0) ? 1 : 0;
    r1 += (ks > k1) ? 1 : 0;
  }
  #pragma unroll
  for (int e = 0; e < 2; ++e) {
    if (fsc[e] > 0.f) {
      int r = (e == 0) ? r0 : r1;
      int so = g * P_ + r;
      scsS[so] = fsc[e];
      ((float4*)ptsS)[so * 2]     = make_float4(fx[e][0], fx[e][1], fx[e][2], fx[e][3]);
      ((float4*)ptsS)[so * 2 + 1] = make_float4(fy[e][0], fy[e][1], fy[e][2], fy[e][3]);
      ((float4*)aabbS)[so] = make_float4(fab[e][0], fab[e][1], fab[e][2], fab[e][3]);
      pr5S[so * 5 + 0] = fp5[e][0]; pr5S[so * 5 + 1] = fp5[e][1];
      pr5S[so * 5 + 2] = fp5[e][2]; pr5S[so * 5 + 3] = fp5[e][3];
      pr5S[so * 5 + 4] = fp5[e][4];
      areaS[so] = far_[e];
    }
  }
  if (tid == 0) gV[g] = cnt;
}

// ---------------------------------------------------------------------------
// exact convex quad-quad intersection area — register-resident, bit-identical
// float op order vs reference (fp contract off). Clips quad q by edges of r.
// ---------------------------------------------------------------------------
__device__ __forceinline__ float inter_area_reg(const float qx[4], const float qy[4],
                                                const float rx[4], const float ry[4]) {
  float px_[8], py_[8];
  #pragma unroll
  for (int t = 0; t < 8; ++t) { px_[t] = (t < 4) ? qx[t] : 0.f; py_[t] = (t < 4) ? qy[t] : 0.f; }
  int n = 4;
  #pragma unroll
  for (int e = 0; e < 4; ++e) {
    float a0 = rx[e], a1 = ry[e];
    float b0 = rx[(e + 1) & 3], b1 = ry[(e + 1) & 3];
    float dx = b0 - a0, dy = b1 - a1;
    float ox_[8], oy_[8];
    #pragma unroll
    for (int t = 0; t < 8; ++t) { ox_[t] = 0.f; oy_[t] = 0.f; }
    float cr[8];
    #pragma unroll
    for (int t = 0; t < 8; ++t) cr[t] = dx * (py_[t] - a1) - dy * (px_[t] - a0);
    int m = 0;
    int nn = (n > 1) ? n : 1;
    #pragma unroll
    for (int t = 0; t < 8; ++t) {
      bool act = t < n;
      float sx = px_[t], sy = py_[t];
      float ex, ey, ce;
      if (t == 7) { ex = px_[0]; ey = py_[0]; ce = cr[0]; }
      else {
        bool wrap = (t + 1 == nn);
        ex = wrap ? px_[0] : px_[t + 1];
        ey = wrap ? py_[0] : py_[t + 1];
        ce = wrap ? cr[0] : cr[t + 1];
      }
      float cs = cr[t];
      float denom = cs - ce;
      float dn = (fabsf(denom) > 1e-12f) ? denom : 1e-12f;
      float tt = cs / dn;
      float ipx = sx + tt * (ex - sx);
      float ipy = sy + tt * (ey - sy);
      bool s_in = cs >= 0.f, e_in = ce >= 0.f;
      bool app1 = act && (s_in != e_in);
      #pragma unroll
      for (int s2 = 0; s2 < 8; ++s2) {
        bool wr = app1 && (m == s2);
        ox_[s2] = wr ? ipx : ox_[s2];
        oy_[s2] = wr ? ipy : oy_[s2];
      }
      m += app1 ? 1 : 0;
      bool app2 = act && e_in;
      #pragma unroll
      for (int s2 = 0; s2 < 8; ++s2) {
        bool wr = app2 && (m == s2);
        ox_[s2] = wr ? ex : ox_[s2];
        oy_[s2] = wr ? ey : oy_[s2];
      }
      m += app2 ? 1 : 0;
    }
    n = m;
    #pragma unroll
    for (int t = 0; t < 8; ++t) { px_[t] = ox_[t]; py_[t] = oy_[t]; }
  }
  int nn = (n > 1) ? n : 1;
  float s = 0.f;
  #pragma unroll
  for (int t = 0; t < 8; ++t) {
    if (t < n) {
      float nx_x, nx_y;
      if (t == 7) { nx_x = px_[0]; nx_y = py_[0]; }
      else {
        bool wrap = (t + 1 == nn);
        nx_x = wrap ? px_[0] : px_[t + 1];
        nx_y = wrap ? py_[0] : py_[t + 1];
      }
      s += px_[t] * nx_y - nx_x * py_[t];
    }
  }
  float area = 0.5f * fabsf(s);
  return (n >= 3) ? area : 0.f;
}

// ---------------------------------------------------------------------------
// K2 (pair): AABB-filter + LDS-compact + dense IoU over surviving pairs.
// grid = (NBX, 40), chunk-strided over the valid-prefix tri domain.
// ---------------------------------------------------------------------------
__global__ void __launch_bounds__(256)
pair_kernel(const int* __restrict__ gV,
            const float* __restrict__ aabbS,
            const float* __restrict__ areaS,
            const float* __restrict__ ptsS,
            u64* __restrict__ sup) {
  int g = blockIdx.y;
  int V = gV[g];
  int Tp = V * (V - 1) / 2;
  int tid = threadIdx.x;
  __shared__ u32 q[CHUNK];
  __shared__ int qn;
  const float4* ab = (const float4*)aabbS;
  const float4* pS = (const float4*)ptsS;

  for (int ch = blockIdx.x; ch * CHUNK < Tp; ch += NBX) {
    int base = ch * CHUNK;
    if (tid == 0) qn = 0;
    __syncthreads();
    #pragma unroll
    for (int t = 0; t < 4; ++t) {
      int kk = base + t * TPB + tid;
      if (kk >= Tp) break;
      float kf = (float)kk;
      int i = (int)((1.0f + sqrtf(1.0f + 8.0f * kf)) * 0.5f);
      while (i * (i - 1) / 2 > kk) --i;
      while ((i + 1) * i / 2 <= kk) ++i;
      int j = kk - i * (i - 1) / 2;
      float4 bi = ab[g * P_ + i];
      float4 bj = ab[g * P_ + j];
      bool ov = (bi.x <= bj.z) && (bj.x <= bi.z) && (bi.y <= bj.w) && (bj.y <= bi.w);
      if (ov) {
        int s = atomicAdd(&qn, 1);
        q[s] = (u32)((i << 9) | j);
      }
    }
    __syncthreads();
    int nq = qn;
    for (int s = tid; s < nq; s += TPB) {
      u32 pk = q[s];
      int i = (int)(pk >> 9), j = (int)(pk & 511);
      float4 ax = pS[(g * P_ + i) * 2];
      float4 ay = pS[(g * P_ + i) * 2 + 1];
      float4 bx = pS[(g * P_ + j) * 2];
      float4 by = pS[(g * P_ + j) * 2 + 1];
      float qx[4] = {ax.x, ax.y, ax.z, ax.w};
      float qy[4] = {ay.x, ay.y, ay.z, ay.w};
      float rx[4] = {bx.x, bx.y, bx.z, bx.w};
      float ry[4] = {by.x, by.y, by.z, by.w};
      float ai = areaS[g * P_ + i];
      float aj = areaS[g * P_ + j];
      // reference iou[i][j]: clip quad i by edges of quad j
      float inter = inter_area_reg(qx, qy, rx, ry);
      float iou = inter / (((ai + aj) - inter) + 1e-8f);
      if (iou > NMS_THR)
        atomicOr(&sup[((size_t)g * P_ + i) * 8 + (j >> 6)], 1ull << (j & 63));
    }
    __syncthreads();
  }
}

// ---------------------------------------------------------------------------
// K3 (greedy+rank): per-group greedy over bitmask rows + emit cand/rec;
// last-arriving group per image (40-block arrival counter — cheap at this
// scale) runs the per-image binary-search top-100 and writes the output.
// out layout: bb[2,100,4] | rr[2,100,5] | sc[2,100] | lab[2,100] (all f32)
// ---------------------------------------------------------------------------
__global__ void __launch_bounds__(256)
greedy_kernel(const float* __restrict__ scsS, const int* __restrict__ gV,
              const float* __restrict__ aabbS, const float* __restrict__ pr5S,
              const u64* __restrict__ sup,
              u64* __restrict__ cand, float* __restrict__ rec,
              int* __restrict__ grpCnt, float* __restrict__ out) {
  int g = blockIdx.x;
  int tid = threadIdx.x;
  __shared__ u64 shbuf[P_ * 8];    // 32 KB: lsup, later aliased as lc[NC]
  __shared__ u32 skeep[16];
  __shared__ int scnt;
  __shared__ int amLast;
  int V = gV[g];
  for (int w = tid; w < V * 8; w += TPB) shbuf[w] = sup[(size_t)g * P_ * 8 + w];
  __syncthreads();
  if (tid < 64) {
    u64 keepw = 0;
    u64 cur = (tid < 8 && V > 0) ? shbuf[tid] : 0ull;
    for (int i = 0; i < V; ++i) {
      u64 nxt = (tid < 8 && (i + 1) < V) ? shbuf[(i + 1) * 8 + tid] : 0ull;  // prefetch
      bool supd = __any((cur & keepw) != 0ull);
      if (!supd && tid == (i >> 6)) keepw |= 1ull << (i & 63);
      cur = nxt;
    }
    if (tid < 8) { skeep[tid * 2] = (u32)keepw; skeep[tid * 2 + 1] = (u32)(keepw >> 32); }
  }
  __syncthreads();
  int cls = g % CF;
  int tot = 0;
  #pragma unroll
  for (int t = 0; t < 16; ++t) tot += __popc(skeep[t]);
  for (int r = tid; r < V; r += TPB) {
    if ((skeep[r >> 5] >> (r & 31)) & 1u) {
      int slot = __popc(skeep[r >> 5] & ((1u << (r & 31)) - 1u));
      for (int t = 0; t < (r >> 5); ++t) slot += __popc(skeep[t]);
      if (slot < DET) {
        float sv = scsS[g * P_ + r];
        int flat = cls * P_ + r;
        cand[g * DET + slot] = ((u64)f2o(sv) << 32) | (u32)(~(u32)flat);
        int so = g * P_ + r;
        float* rr = rec + (size_t)(g * DET + slot) * 12;
        rr[0] = fminf(fmaxf(aabbS[so * 4 + 0], 0.f), 1023.0f);
        rr[1] = fminf(fmaxf(aabbS[so * 4 + 1], 0.f), 799.0f);
        rr[2] = fminf(fmaxf(aabbS[so * 4 + 2], 0.f), 1023.0f);
        rr[3] = fminf(fmaxf(aabbS[so * 4 + 3], 0.f), 799.0f);
        rr[4] = pr5S[so * 5 + 0]; rr[5] = pr5S[so * 5 + 1]; rr[6] = pr5S[so * 5 + 2];
        rr[7] = pr5S[so * 5 + 3]; rr[8] = pr5S[so * 5 + 4];
        rr[9] = sv;
        rr[10] = (float)(cls + 1);
        rr[11] = 0.f;
      }
    }
  }
  int fill = tot < DET ? tot : DET;
  for (int s = fill + tid; s < DET; s += TPB) cand[g * DET + s] = 0ull;

  // ---- arrival; last of the 20 groups per image runs the rank phase ----
  __syncthreads();
  __threadfence();                               // release cand/rec (40 fences total)
  int b = g / CF;
  if (tid == 0) amLast = (atomicAdd(&grpCnt[b], 1) == CF - 1) ? 1 : 0;
  __syncthreads();
  if (!amLast) return;
  __threadfence();                               // acquire other groups' cand/rec

  u64* lc = shbuf;                               // alias (16 KB)
  if (tid == 0) scnt = 0;
  __syncthreads();
  int nz = 0;
  for (int i = tid; i < NC; i += TPB) {
    u64 v = cand[b * NC + i];
    lc[i] = v;
    nz += (v != 0ull) ? 1 : 0;
  }
  if (nz > 0) atomicAdd(&scnt, nz);
  __syncthreads();
  int nc = scnt;
  for (int row = nc + tid; row < DET; row += TPB) {
    int o_bb = (b * DET + row) * 4;
    int o_rr = B_ * DET * 4 + (b * DET + row) * 5;
    int o_sc = B_ * DET * 9 + b * DET + row;
    int o_lab = B_ * DET * 10 + b * DET + row;
    out[o_bb + 0] = 0.f; out[o_bb + 1] = 0.f; out[o_bb + 2] = 0.f; out[o_bb + 3] = 0.f;
    out[o_rr + 0] = 0.f; out[o_rr + 1] = 0.f; out[o_rr + 2] = 0.f;
    out[o_rr + 3] = 0.f; out[o_rr + 4] = 0.f;
    out[o_sc] = 0.f;
    out[o_lab] = 0.f;
  }
  for (int ci = tid; ci < NC; ci += TPB) {
    u64 k = lc[ci];
    if (k == 0ull) continue;
    int rank = 0;
    #pragma unroll
    for (int gp = 0; gp < CF; ++gp) {
      int lo = 0, hi = DET;
      while (lo < hi) {          // first idx with lc[gp*DET+idx] <= k (desc)
        int mid = (lo + hi) >> 1;
        if (lc[gp * DET + mid] > k) lo = mid + 1; else hi = mid;
      }
      rank += lo;
    }
    if (rank >= DET) continue;
    const float* rr = rec + (size_t)(b * NC + ci) * 12;
    int o_bb = (b * DET + rank) * 4;
    int o_rr = B_ * DET * 4 + (b * DET + rank) * 5;
    int o_sc = B_ * DET * 9 + b * DET + rank;
    int o_lab = B_ * DET * 10 + b * DET + rank;
    out[o_bb + 0] = rr[0]; out[o_bb + 1] = rr[1];
    out[o_bb + 2] = rr[2]; out[o_bb + 3] = rr[3];
    out[o_rr + 0] = rr[4]; out[o_rr + 1] = rr[5]; out[o_rr + 2] = rr[6];
    out[o_rr + 3] = rr[7]; out[o_rr + 4] = rr[8];
    out[o_sc] = rr[9];
    out[o_lab] = rr[10];
  }
}

// ---------------------------------------------------------------------------
extern "C" void kernel_launch(void* const* d_in, const int* in_sizes, int n_in,
                              void* d_out, int out_size, void* d_ws, size_t ws_size,
                              hipStream_t stream) {
  const float* logits = (const float*)d_in[0];
  const float* breg   = (const float*)d_in[1];
  const float* rrects = (const float*)d_in[2];
  float* out = (float*)d_out;

  u64*   sup    = (u64*)d_ws;                         // G*P*8 u64
  u64*   cand   = sup + (size_t)G_ * P_ * 8;          // G*DET u64
  int*   gV     = (int*)(cand + G_ * DET);            // 64 ints
  int*   grpCnt = gV + 64;                            // 16 ints
  float* scsS   = (float*)(grpCnt + 16);              // G*P
  float* ptsS   = scsS + (size_t)G_ * P_;             // G*P*8
  float* aabbS  = ptsS + (size_t)G_ * P_ * 8;         // G*P*4
  float* pr5S   = aabbS + (size_t)G_ * P_ * 4;        // G*P*5
  float* areaS  = pr5S + (size_t)G_ * P_ * 5;         // G*P
  float* rec    = areaS + (size_t)G_ * P_;            // G*DET*12

  prep_kernel<<<G_, 256, 0, stream>>>(logits, breg, rrects,
                                      scsS, ptsS, aabbS, pr5S, areaS, gV, sup,
                                      grpCnt);
  pair_kernel<<<dim3(NBX, G_), TPB, 0, stream>>>(gV, aabbS, areaS, ptsS, sup);
  greedy_kernel<<<G_, TPB, 0, stream>>>(scsS, gV, aabbS, pr5S, sup, cand, rec,
                                        grpCnt, out);
}

// Round 11
// 148.736 us; speedup vs baseline: 3.1990x; 1.2358x over previous
//
#include <hip/hip_runtime.h>
#include <stdint.h>

#pragma clang fp contract(off)

#define B_ 2
#define P_ 512
#define C_ 21
#define CF 20            // foreground classes
#define G_ (B_ * CF)     // 40 groups
#define DET 100
#define SCORE_THRESH 0.05f
#define NMS_THR 0.5f
#define BBOX_CLIP 4.135166556742356f   // log(1000/16)
#define NC (CF * DET)    // 2000 candidates per image
#define TPB 256
#define NBX 32           // pair blocks per group (chunk-strided)
#define CHUNK 1024       // pairs per chunk
#define MAXCH 128        // max chunks per group (tri(512)/1024)

typedef unsigned long long u64;
typedef unsigned int u32;

__device__ __forceinline__ u32 f2o(float f) {
  u32 u = __float_as_uint(f);
  return (u & 0x80000000u) ? ~u : (u | 0x80000000u);
}

// ---------------------------------------------------------------------------
// exact convex quad-quad intersection area — register-resident, bit-identical
// float op order vs reference (fp contract off). Clips quad q by edges of r.
// ---------------------------------------------------------------------------
__device__ __forceinline__ float inter_area_reg(const float qx[4], const float qy[4],
                                                const float rx[4], const float ry[4]) {
  float px_[8], py_[8];
  #pragma unroll
  for (int t = 0; t < 8; ++t) { px_[t] = (t < 4) ? qx[t] : 0.f; py_[t] = (t < 4) ? qy[t] : 0.f; }
  int n = 4;
  #pragma unroll
  for (int e = 0; e < 4; ++e) {
    float a0 = rx[e], a1 = ry[e];
    float b0 = rx[(e + 1) & 3], b1 = ry[(e + 1) & 3];
    float dx = b0 - a0, dy = b1 - a1;
    float ox_[8], oy_[8];
    #pragma unroll
    for (int t = 0; t < 8; ++t) { ox_[t] = 0.f; oy_[t] = 0.f; }
    float cr[8];
    #pragma unroll
    for (int t = 0; t < 8; ++t) cr[t] = dx * (py_[t] - a1) - dy * (px_[t] - a0);
    int m = 0;
    int nn = (n > 1) ? n : 1;
    #pragma unroll
    for (int t = 0; t < 8; ++t) {
      bool act = t < n;
      float sx = px_[t], sy = py_[t];
      float ex, ey, ce;
      if (t == 7) { ex = px_[0]; ey = py_[0]; ce = cr[0]; }
      else {
        bool wrap = (t + 1 == nn);
        ex = wrap ? px_[0] : px_[t + 1];
        ey = wrap ? py_[0] : py_[t + 1];
        ce = wrap ? cr[0] : cr[t + 1];
      }
      float cs = cr[t];
      float denom = cs - ce;
      float dn = (fabsf(denom) > 1e-12f) ? denom : 1e-12f;
      float tt = cs / dn;
      float ipx = sx + tt * (ex - sx);
      float ipy = sy + tt * (ey - sy);
      bool s_in = cs >= 0.f, e_in = ce >= 0.f;
      bool app1 = act && (s_in != e_in);
      #pragma unroll
      for (int s2 = 0; s2 < 8; ++s2) {
        bool wr = app1 && (m == s2);
        ox_[s2] = wr ? ipx : ox_[s2];
        oy_[s2] = wr ? ipy : oy_[s2];
      }
      m += app1 ? 1 : 0;
      bool app2 = act && e_in;
      #pragma unroll
      for (int s2 = 0; s2 < 8; ++s2) {
        bool wr = app2 && (m == s2);
        ox_[s2] = wr ? ex : ox_[s2];
        oy_[s2] = wr ? ey : oy_[s2];
      }
      m += app2 ? 1 : 0;
    }
    n = m;
    #pragma unroll
    for (int t = 0; t < 8; ++t) { px_[t] = ox_[t]; py_[t] = oy_[t]; }
  }
  int nn = (n > 1) ? n : 1;
  float s = 0.f;
  #pragma unroll
  for (int t = 0; t < 8; ++t) {
    if (t < n) {
      float nx_x, nx_y;
      if (t == 7) { nx_x = px_[0]; nx_y = py_[0]; }
      else {
        bool wrap = (t + 1 == nn);
        nx_x = wrap ? px_[0] : px_[t + 1];
        nx_y = wrap ? py_[0] : py_[t + 1];
      }
      s += px_[t] * nx_y - nx_x * py_[t];
    }
  }
  float area = 0.5f * fabsf(s);
  return (n >= 3) ? area : 0.f;
}

// ---------------------------------------------------------------------------
// D1 (pairdec): 32 blocks per group. Each block redundantly decodes + rank-
// sorts its group in LDS (valid-prefix sorted space), then processes its
// strided share of the tri(V) pair domain: AABB reject -> LDS queue -> exact
// clip. Suppressing pairs go to per-chunk compact lists (count written
// unconditionally) => no global atomics, nothing needs pre-zeroing.
// Block x==0 publishes sorted scores/aabb/pr5 and V for D2/D3.
// ---------------------------------------------------------------------------
__global__ void __launch_bounds__(256)
pairdec_kernel(const float* __restrict__ logits,
               const float* __restrict__ breg,
               const float* __restrict__ rrects,
               u32* __restrict__ nsup,    // [G*MAXCH] per-chunk counts
               u32* __restrict__ list,    // [G*MAXCH*CHUNK] pair lists
               int* __restrict__ gV,
               float* __restrict__ scsS,  // [G*P] sorted scores
               float* __restrict__ aabbS, // [G*P][4] sorted unclipped aabb
               float* __restrict__ pr5S) {// [G*P][5] sorted proposals
  int g = blockIdx.y;
  int bx = blockIdx.x;
  int tid = threadIdx.x;
  int b = g / CF, cf = g % CF, c = cf + 1;

  __shared__ u64 lkey[P_];          // 4 KB
  __shared__ float lptx[4][P_];     // 8 KB  (sorted corner xs, SoA)
  __shared__ float lpty[4][P_];     // 8 KB
  __shared__ float lab4[4][P_];     // 8 KB  (minx,miny,maxx,maxy, SoA)
  __shared__ float larea[P_];       // 2 KB
  __shared__ u32 q[CHUNK];          // 4 KB
  __shared__ int qn, sn, sV;
  if (tid == 0) sV = 0;

  // ---- decode 2 proposals/thread (identical arithmetic to reference) ----
  u64 kreg[2];
  float fx[2][4], fy[2][4], fab[2][4], fp5[2][5], far_[2], fsc[2];
  #pragma unroll
  for (int e = 0; e < 2; ++e) {
    int p = tid + e * 256;
    int n = b * P_ + p;
    const float* lg = logits + n * C_;
    float mx = lg[0];
    for (int k = 1; k < C_; ++k) mx = fmaxf(mx, lg[k]);
    float den = 0.f;
    for (int k = 0; k < C_; ++k) den += expf(lg[k] - mx);
    float sc = expf(lg[c] - mx) / den;

    const float* d = breg + n * (C_ * 5) + c * 5;
    float dx = d[0] / 10.0f, dy = d[1] / 10.0f;
    float dw = d[2] / 5.0f, dh = d[3] / 5.0f, da = d[4] / 3.0f;
    dw = fminf(dw, BBOX_CLIP);
    dh = fminf(dh, BBOX_CLIP);
    const float* an = rrects + n * 5;
    float px = dx * an[2] + an[0];
    float py = dy * an[3] + an[1];
    float pw = expf(dw) * an[2];
    float ph = expf(dh) * an[3];
    float pa = da * 57.29577951308232f + an[4];
    fp5[e][0] = px; fp5[e][1] = py; fp5[e][2] = pw; fp5[e][3] = ph; fp5[e][4] = pa;
    far_[e] = pw * ph;

    float t = pa * 0.017453292519943295f;
    float cs = cosf(t), sn2 = sinf(t);
    float hx = pw * 0.5f, hy = ph * 0.5f;
    float ox[4] = {-hx, hx, hx, -hx};
    float oy[4] = {-hy, -hy, hy, hy};
    float minx = 1e30f, miny = 1e30f, maxx = -1e30f, maxy = -1e30f;
    #pragma unroll
    for (int qq = 0; qq < 4; ++qq) {
      float x = px + cs * ox[qq] - sn2 * oy[qq];
      float y = py + sn2 * ox[qq] + cs * oy[qq];
      fx[e][qq] = x; fy[e][qq] = y;
      minx = fminf(minx, x); maxx = fmaxf(maxx, x);
      miny = fminf(miny, y); maxy = fmaxf(maxy, y);
    }
    fab[e][0] = minx; fab[e][1] = miny; fab[e][2] = maxx; fab[e][3] = maxy;

    bool valid = sc > SCORE_THRESH;
    float v = valid ? sc : -1.0f;
    fsc[e] = v;
    u64 key = ((u64)f2o(v) << 32) | (u32)(~(u32)p);
    lkey[p] = key;
    kreg[e] = key;
    u64 m = __ballot(valid);
    if ((tid & 63) == 0) atomicAdd(&sV, __popcll(m));
  }
  __syncthreads();

  // ---- rank (keys distinct) + scatter into sorted LDS arrays ----
  u64 k0 = kreg[0], k1 = kreg[1];
  int r0 = 0, r1 = 0;
  for (int s = 0; s < P_; ++s) {
    u64 ks = lkey[s];                // broadcast read
    r0 += (ks > k0) ? 1 : 0;
    r1 += (ks > k1) ? 1 : 0;
  }
  #pragma unroll
  for (int e = 0; e < 2; ++e) {
    int r = (e == 0) ? r0 : r1;
    #pragma unroll
    for (int qq = 0; qq < 4; ++qq) {
      lptx[qq][r] = fx[e][qq];
      lpty[qq][r] = fy[e][qq];
      lab4[qq][r] = fab[e][qq];
    }
    larea[r] = far_[e];
    if (bx == 0) {                   // publish sorted payload once per group
      int so = g * P_ + r;
      scsS[so] = fsc[e];
      ((float4*)aabbS)[so] = make_float4(fab[e][0], fab[e][1], fab[e][2], fab[e][3]);
      pr5S[so * 5 + 0] = fp5[e][0]; pr5S[so * 5 + 1] = fp5[e][1];
      pr5S[so * 5 + 2] = fp5[e][2]; pr5S[so * 5 + 3] = fp5[e][3];
      pr5S[so * 5 + 4] = fp5[e][4];
    }
  }
  __syncthreads();
  int V = sV;
  if (bx == 0 && tid == 0) gV[g] = V;
  int Tp = V * (V - 1) / 2;

  // ---- zero owned count slots unconditionally ----
  for (int ch = bx; ch < MAXCH; ch += NBX)
    if (tid == 0) nsup[g * MAXCH + ch] = 0;

  // ---- chunk-strided pair domain over the valid prefix ----
  for (int ch = bx; ch * CHUNK < Tp; ch += NBX) {
    int base = ch * CHUNK;
    if (tid == 0) { qn = 0; sn = 0; }
    __syncthreads();
    #pragma unroll
    for (int t = 0; t < 4; ++t) {
      int kk = base + t * TPB + tid;
      if (kk >= Tp) break;
      float kf = (float)kk;
      int i = (int)((1.0f + sqrtf(1.0f + 8.0f * kf)) * 0.5f);
      while (i * (i - 1) / 2 > kk) --i;
      while ((i + 1) * i / 2 <= kk) ++i;
      int j = kk - i * (i - 1) / 2;
      bool ov = (lab4[0][i] <= lab4[2][j]) && (lab4[0][j] <= lab4[2][i]) &&
                (lab4[1][i] <= lab4[3][j]) && (lab4[1][j] <= lab4[3][i]);
      if (ov) {
        int s = atomicAdd(&qn, 1);
        q[s] = (u32)((i << 9) | j);
      }
    }
    __syncthreads();
    int nq = qn;
    u32* Lout = list + ((size_t)g * MAXCH + ch) * CHUNK;
    for (int s = tid; s < nq; s += TPB) {
      u32 pk = q[s];
      int i = (int)(pk >> 9), j = (int)(pk & 511);
      float qx[4] = {lptx[0][i], lptx[1][i], lptx[2][i], lptx[3][i]};
      float qy[4] = {lpty[0][i], lpty[1][i], lpty[2][i], lpty[3][i]};
      float rx[4] = {lptx[0][j], lptx[1][j], lptx[2][j], lptx[3][j]};
      float ry[4] = {lpty[0][j], lpty[1][j], lpty[2][j], lpty[3][j]};
      float ai = larea[i];
      float aj = larea[j];
      // reference iou[i][j]: clip quad i (lower-scored) by edges of quad j
      float inter = inter_area_reg(qx, qy, rx, ry);
      float iou = inter / (((ai + aj) - inter) + 1e-8f);
      if (iou > NMS_THR) {
        int idx = atomicAdd(&sn, 1);
        Lout[idx] = pk;
      }
    }
    __syncthreads();
    if (tid == 0) nsup[g * MAXCH + ch] = (u32)sn;
  }
}

// ---------------------------------------------------------------------------
// D2 (greedy): per-group — compact lists -> rank-space LDS bitmatrix ->
// wave-0 greedy ballot chain -> emit cand keys + 12-float records.
// ---------------------------------------------------------------------------
__global__ void __launch_bounds__(256)
greedy_kernel(const u32* __restrict__ nsup, const u32* __restrict__ list,
              const int* __restrict__ gV, const float* __restrict__ scsS,
              const float* __restrict__ aabbS, const float* __restrict__ pr5S,
              u64* __restrict__ cand, float* __restrict__ rec) {
  int g = blockIdx.x;
  int tid = threadIdx.x;
  __shared__ u32 supb[P_][16];      // 32 KB rank-space bitmatrix
  __shared__ u32 lnsup[MAXCH];
  __shared__ u32 skeep[16];
  int V = gV[g];
  for (int w = tid; w < P_ * 16; w += TPB) ((u32*)supb)[w] = 0u;
  for (int i = tid; i < MAXCH; i += TPB) lnsup[i] = nsup[g * MAXCH + i];
  __syncthreads();

  for (int ch = 0; ch < MAXCH; ++ch) {
    int n = (int)lnsup[ch];
    if (n == 0) continue;
    const u32* L = list + ((size_t)g * MAXCH + ch) * CHUNK;
    for (int e = tid; e < n; e += TPB) {
      u32 pk = L[e];
      int i = (int)(pk >> 9), j = (int)(pk & 511);
      atomicOr(&supb[i][j >> 5], 1u << (j & 31));
    }
  }
  __syncthreads();

  if (tid < 64) {
    u32 keepw = 0;
    u32 cur = (tid < 16 && V > 0) ? supb[0][tid] : 0u;
    for (int i = 0; i < V; ++i) {
      u32 nxt = (tid < 16 && (i + 1) < V) ? supb[i + 1][tid] : 0u;  // prefetch
      bool supd = __any((cur & keepw) != 0u);
      if (!supd && tid == (i >> 5)) keepw |= 1u << (i & 31);
      cur = nxt;
    }
    if (tid < 16) skeep[tid] = keepw;
  }
  __syncthreads();

  int cls = g % CF;
  int tot = 0;
  #pragma unroll
  for (int t = 0; t < 16; ++t) tot += __popc(skeep[t]);
  for (int r = tid; r < V; r += TPB) {
    if ((skeep[r >> 5] >> (r & 31)) & 1u) {
      int slot = __popc(skeep[r >> 5] & ((1u << (r & 31)) - 1u));
      for (int t = 0; t < (r >> 5); ++t) slot += __popc(skeep[t]);
      if (slot < DET) {
        float sv = scsS[g * P_ + r];
        int flat = cls * P_ + r;
        cand[g * DET + slot] = ((u64)f2o(sv) << 32) | (u32)(~(u32)flat);
        int so = g * P_ + r;
        float* rr = rec + (size_t)(g * DET + slot) * 12;
        rr[0] = fminf(fmaxf(aabbS[so * 4 + 0], 0.f), 1023.0f);
        rr[1] = fminf(fmaxf(aabbS[so * 4 + 1], 0.f), 799.0f);
        rr[2] = fminf(fmaxf(aabbS[so * 4 + 2], 0.f), 1023.0f);
        rr[3] = fminf(fmaxf(aabbS[so * 4 + 3], 0.f), 799.0f);
        rr[4] = pr5S[so * 5 + 0]; rr[5] = pr5S[so * 5 + 1]; rr[6] = pr5S[so * 5 + 2];
        rr[7] = pr5S[so * 5 + 3]; rr[8] = pr5S[so * 5 + 4];
        rr[9] = sv;
        rr[10] = (float)(cls + 1);
        rr[11] = 0.f;
      }
    }
  }
  int fill = tot < DET ? tot : DET;
  for (int s = fill + tid; s < DET; s += TPB) cand[g * DET + s] = 0ull;
}

// ---------------------------------------------------------------------------
// D3 (rank): per-image top-100 by binary-search rank; scatter record to row
// `rank`; zero-fill unused rows in-kernel.
// out layout: bb[2,100,4] | rr[2,100,5] | sc[2,100] | lab[2,100] (all f32)
// ---------------------------------------------------------------------------
__global__ void rank_kernel(const u64* __restrict__ cand, const float* __restrict__ rec,
                            float* __restrict__ out) {
  int b = blockIdx.y;
  int tid = threadIdx.x;
  __shared__ u64 lc[NC];
  __shared__ int ncand;
  if (tid == 0) ncand = 0;
  __syncthreads();
  int nz = 0;
  for (int i = tid; i < NC; i += 256) {
    u64 v = cand[b * NC + i];
    lc[i] = v;
    nz += (v != 0ull) ? 1 : 0;
  }
  if (nz > 0) atomicAdd(&ncand, nz);
  __syncthreads();
  int ci = blockIdx.x * 256 + tid;
  if (ci >= NC) return;
  int nc = ncand;
  if (blockIdx.x == 0 && tid < DET && tid >= nc) {
    int o_bb = (b * DET + tid) * 4;
    int o_rr = B_ * DET * 4 + (b * DET + tid) * 5;
    int o_sc = B_ * DET * 9 + b * DET + tid;
    int o_lab = B_ * DET * 10 + b * DET + tid;
    out[o_bb + 0] = 0.f; out[o_bb + 1] = 0.f; out[o_bb + 2] = 0.f; out[o_bb + 3] = 0.f;
    out[o_rr + 0] = 0.f; out[o_rr + 1] = 0.f; out[o_rr + 2] = 0.f;
    out[o_rr + 3] = 0.f; out[o_rr + 4] = 0.f;
    out[o_sc] = 0.f;
    out[o_lab] = 0.f;
  }
  u64 k = lc[ci];
  if (k == 0ull) return;
  int rank = 0;
  #pragma unroll
  for (int gp = 0; gp < CF; ++gp) {
    int lo = 0, hi = DET;
    while (lo < hi) {            // first idx with lc[gp*DET+idx] <= k (desc list)
      int mid = (lo + hi) >> 1;
      if (lc[gp * DET + mid] > k) lo = mid + 1; else hi = mid;
    }
    rank += lo;
  }
  if (rank >= DET) return;
  const float* rr = rec + (size_t)(b * NC + ci) * 12;
  int o_bb = (b * DET + rank) * 4;
  int o_rr = B_ * DET * 4 + (b * DET + rank) * 5;
  int o_sc = B_ * DET * 9 + b * DET + rank;
  int o_lab = B_ * DET * 10 + b * DET + rank;
  out[o_bb + 0] = rr[0]; out[o_bb + 1] = rr[1];
  out[o_bb + 2] = rr[2]; out[o_bb + 3] = rr[3];
  out[o_rr + 0] = rr[4]; out[o_rr + 1] = rr[5]; out[o_rr + 2] = rr[6];
  out[o_rr + 3] = rr[7]; out[o_rr + 4] = rr[8];
  out[o_sc] = rr[9];
  out[o_lab] = rr[10];
}

// ---------------------------------------------------------------------------
extern "C" void kernel_launch(void* const* d_in, const int* in_sizes, int n_in,
                              void* d_out, int out_size, void* d_ws, size_t ws_size,
                              hipStream_t stream) {
  const float* logits = (const float*)d_in[0];
  const float* breg   = (const float*)d_in[1];
  const float* rrects = (const float*)d_in[2];
  float* out = (float*)d_out;

  u32*   nsup  = (u32*)d_ws;                              // G*MAXCH
  u32*   list  = nsup + (size_t)G_ * MAXCH;               // G*MAXCH*CHUNK (20 MB)
  u64*   cand  = (u64*)(list + (size_t)G_ * MAXCH * CHUNK);
  int*   gV    = (int*)(cand + G_ * DET);                 // 64 ints
  float* scsS  = (float*)(gV + 64);                       // G*P
  float* aabbS = scsS + (size_t)G_ * P_;                  // G*P*4
  float* pr5S  = aabbS + (size_t)G_ * P_ * 4;             // G*P*5
  float* rec   = pr5S + (size_t)G_ * P_ * 5;              // G*DET*12

  pairdec_kernel<<<dim3(NBX, G_), TPB, 0, stream>>>(logits, breg, rrects,
                                                    nsup, list, gV,
                                                    scsS, aabbS, pr5S);
  greedy_kernel<<<G_, TPB, 0, stream>>>(nsup, list, gV, scsS, aabbS, pr5S,
                                        cand, rec);
  rank_kernel<<<dim3(8, B_), 256, 0, stream>>>(cand, rec, out);
}